// Round 16
// baseline (451.512 us; speedup 1.0000x reference)
//
#include <hip/hip_runtime.h>
#include <hip/hip_bf16.h>
#include <math.h>

#define NN 20000
#define NE 320000
#define NG 200
#define FI 75
#define NT 5
#define FO 15
#define CH 375     // NT*FI
#define PI 975

typedef __attribute__((ext_vector_type(8))) short v8s;
typedef __attribute__((ext_vector_type(4))) float v4f;

__device__ __forceinline__ unsigned short f2bfu(float v) {
  __hip_bfloat16 h = __float2bfloat16(v);
  return *reinterpret_cast<unsigned short*>(&h);
}
__device__ __forceinline__ float uif(unsigned u) { return __uint_as_float(u); }

// ================= prep mega kernels =================
// mega1 (256 thr): gather_x | count | table_e | repack_WAs | make_V | bias_comb
__global__ __launch_bounds__(256) void k_mega1(
    const int* __restrict__ xidx, const float* __restrict__ emb, float* __restrict__ x,
    const int* __restrict__ dstp, int* __restrict__ deg,
    const float* __restrict__ eemb, const float* __restrict__ W_edge,
    const float* __restrict__ b_edge, float* __restrict__ te,
    const float* __restrict__ W_pre, float* __restrict__ WAs,
    const float* __restrict__ W_post, float* __restrict__ V,
    const float* __restrict__ b_post, const float* __restrict__ W_lin,
    const float* __restrict__ b_lin, float* __restrict__ bc) {
  __shared__ float S[FI * 16];
  int b = blockIdx.x, tid = threadIdx.x;
  if (b < 5860) {                       // gather_x
    int i = b * 256 + tid;
    if (i < NN * FI) {
      int n = i / FI, f = i - n * FI;
      x[i] = emb[xidx[n] * FI + f];
    }
  } else if (b < 7110) {                // count
    int e = (b - 5860) * 256 + tid;
    if (e < NE) atomicAdd(&deg[dstp[e]], 1);
  } else if (b < 7310) {                // table_e
    int la = b - 7110;
    int l = la / 100, a = la - l * 100;
    int f = tid;
    if (f < FI) {
      float acc = b_edge[l * FI + f];
      for (int j = 0; j < 50; ++j)
        acc = fmaf(eemb[a * 50 + j], W_edge[(l * 50 + j) * FI + f], acc);
      te[la * FI + f] = acc;
    }
  } else if (b < 7530) {                // repack_WAs
    int i = (b - 7310) * 256 + tid;
    if (i < 2 * FI * CH) {
      int c = i % CH;
      int k = (i / CH) % FI;
      int l = i / (CH * FI);
      int t = c / FI, f = c - t * FI;
      WAs[i] = W_pre[((size_t)(l * NT + t) * 225 + FI + k) * FI + f];
    }
  } else if (b < 7560) {                // make_V
    int bid = b - 7530;                 // (l*5+t)*3+g
    int g = bid % 3;
    int lt = bid / 3;
    for (int idx = tid; idx < FI * 16; idx += 256) {
      int q = idx >> 4, f = idx & 15;
      float v = 0.f;
      if (f < FO) {
        const float* wb = W_post + (size_t)lt * PI * FO;
        int rowb = FI + g * 300 + q;
        v = wb[rowb * FO + f] + wb[(rowb + FI) * FO + f] + wb[(rowb + 2 * FI) * FO + f];
      }
      S[idx] = v;
    }
    __syncthreads();
    for (int idx = tid; idx < FI * 16; idx += 256) {
      int j = idx >> 4, f = idx & 15;
      float acc = 0.f;
      const float* wr = W_pre + ((size_t)lt * 225 + j) * FI;
      for (int q = 0; q < FI; ++q) acc = fmaf(wr[q], S[q * 16 + f], acc);
      V[((size_t)bid * FI + j) * 16 + f] = acc;
    }
  } else {                              // bias_comb
    int l = b - 7560;
    int g = tid;
    if (g < FI) {
      float acc = b_lin[l * FI + g];
      for (int j = 0; j < FI; ++j)
        acc = fmaf(b_post[l * FI + j], W_lin[(l * FI + j) * FI + g], acc);
      bc[l * 76 + g] = acc;
    }
  }
}

// mega2 (1024 thr): scan | logsum | tbl_m | pack_B | pack_Bxs | pack_Blin
__global__ __launch_bounds__(1024) void k_mega2(
    const int* __restrict__ deg, int* __restrict__ off, int* __restrict__ cur,
    float* __restrict__ avglog,
    const float* __restrict__ te, const float* __restrict__ W_pre,
    const float* __restrict__ b_pre, unsigned short* __restrict__ tm,
    const float* __restrict__ W_post, const float* __restrict__ V,
    unsigned short* __restrict__ Bp,
    const float* __restrict__ WAs, unsigned short* __restrict__ Bxs,
    const float* __restrict__ W_lin, unsigned short* __restrict__ Blin) {
  __shared__ float red[1024];
  int b = blockIdx.x, t = threadIdx.x;
  if (b == 0) {                         // scan: 1024 x 20
    int* wsum = (int*)red;
    int base = t * 20;
    int loc[20];
    int s = 0;
#pragma unroll
    for (int j = 0; j < 20; ++j) {
      int i = base + j;
      int v = (i < NN) ? deg[i] : 0;
      loc[j] = s;
      s += v;
    }
    int lane = t & 63, w = t >> 6;
    int inc = s;
    for (int o = 1; o < 64; o <<= 1) {
      int u = __shfl_up(inc, o, 64);
      if (lane >= o) inc += u;
    }
    if (lane == 63) wsum[w] = inc;
    __syncthreads();
    if (t == 0) {
      int a = 0;
#pragma unroll
      for (int k = 0; k < 16; ++k) { int v = wsum[k]; wsum[k] = a; a += v; }
    }
    __syncthreads();
    int tex = wsum[w] + inc - s;
#pragma unroll
    for (int j = 0; j < 20; ++j) {
      int i = base + j;
      if (i < NN) { int e = tex + loc[j]; off[i] = e; cur[i] = e; }
    }
    if (t == 1023) off[NN] = tex + s;
  } else if (b == 1) {                  // logsum
    float s = 0.f;
    for (int i = t; i < NN; i += 1024) s += logf((float)deg[i] + 1.f);
    red[t] = s;
    __syncthreads();
    for (int o = 512; o > 0; o >>= 1) {
      if (t < o) red[t] += red[t + o];
      __syncthreads();
    }
    if (t == 0) avglog[0] = red[0] / (float)NN;
  } else if (b < 77) {                  // tbl_m flat: 2*100*384
    int idx = (b - 2) * 1024 + t;
    if (idx < 76800) {
      int la = idx / 384, c = idx - la * 384;
      int l = la / 100;
      float acc = 0.f;
      if (c < CH) {
        int tt = c / FI, f = c - tt * FI;
        acc = b_pre[(l * NT + tt) * FI + f];
        const float* ter = te + la * FI;
        for (int k = 0; k < FI; ++k)
          acc = fmaf(ter[k], W_pre[((size_t)(l * NT + tt) * 225 + 150 + k) * FI + f], acc);
      }
      tm[(size_t)la * 384 + c] = f2bfu(acc);
    }
  } else if (b < 302) {                 // pack_B (post MFMA weights)
    int i = (b - 77) * 1024 + t;
    if (i < 230400) {
      int j = i & 7;
      int lane = (i >> 3) & 63;
      int rem = i >> 9;
      int kb = rem % 15; rem /= 15;
      int g = rem % 3; rem /= 3;
      int tt = rem % 5;
      int l = rem / 5;
      int k = kb * 32 + (lane >> 4) * 8 + j;
      int f = lane & 15;
      float w = 0.f;
      if (f < FO) {
        int lt = l * NT + tt;
        if (k < 300) {
          int a = k / 75, ch = k - a * 75;
          w = W_post[((size_t)lt * PI + FI + g * 300 + a * 75 + ch) * FO + f];
        } else if (k >= 320 && k < 395) {
          w = V[(((size_t)(lt * 3 + g)) * FI + (k - 320)) * 16 + f];
        } else if (k >= 395 && k < 470 && g == 0) {
          w = W_post[((size_t)lt * PI + (k - 395)) * FO + f];
        }
      }
      Bp[i] = f2bfu(w);
    }
  } else if (b < 374) {                 // pack_Bxs (xs MFMA weights), 73728 elems
    int i = (b - 302) * 1024 + t;
    if (i < 73728) {
      int j = i & 7;
      int lane = (i >> 3) & 63;
      int rem = i >> 9;                 // 0..143
      int nt = rem % 24; rem /= 24;
      int kb = rem % 3;
      int l = rem / 3;
      int k = kb * 32 + (lane >> 4) * 8 + j;
      int n = nt * 16 + (lane & 15);
      float w = 0.f;
      if (k < FI && n < CH) w = WAs[(size_t)l * FI * CH + k * CH + n];
      Bxs[i] = f2bfu(w);
    }
  } else {                              // pack_Blin (W_lin MFMA weights), 15360 elems
    int i = (b - 374) * 1024 + t;
    if (i < 15360) {
      int j = i & 7;
      int lane = (i >> 3) & 63;
      int rem = i >> 9;                 // 0..29
      int nt = rem % 5; rem /= 5;
      int kb = rem % 3;
      int l = rem / 3;
      int k = kb * 32 + (lane >> 4) * 8 + j;
      int f = nt * 16 + (lane & 15);
      float w = 0.f;
      if (k < FI && f < FI) w = W_lin[(size_t)l * FI * FI + k * FI + f];
      Blin[i] = f2bfu(w);
    }
  }
}

// mega3 (256 thr): fill | scalers
__global__ __launch_bounds__(256) void k_mega3(
    const int* __restrict__ srcp, const int* __restrict__ dstp,
    const int* __restrict__ attr, int* __restrict__ cur, int2* __restrict__ csr,
    const int* __restrict__ deg, const float* __restrict__ avglog,
    float* __restrict__ amp, float* __restrict__ att, float* __restrict__ inv) {
  int b = blockIdx.x, t = threadIdx.x;
  if (b < 1250) {
    int e = b * 256 + t;
    if (e < NE) {
      int pos = atomicAdd(&cur[dstp[e]], 1);
      csr[pos] = make_int2(srcp[e], attr[e]);
    }
  } else {
    int i = (b - 1250) * 256 + t;
    if (i < NN) {
      float dc = fmaxf((float)deg[i], 1.f);
      float ld = logf(dc + 1.f);
      float av = avglog[0];
      amp[i] = ld / av;
      att[i] = av / ld;
      inv[i] = 1.f / dc;
    }
  }
}

// ================= per-layer =================
// y==0: xs_bf[n,0:384] = x@W_pre_src via MFMA.  y==1: build xh + zero bnsum.
__global__ __launch_bounds__(256) void k_gemm_xs(const float* __restrict__ x,
                                                 const unsigned short* __restrict__ BxsL,
                                                 unsigned short* __restrict__ xsb,
                                                 const int* __restrict__ deg,
                                                 unsigned short* __restrict__ xh,
                                                 float* __restrict__ bnsum) {
  int tid = threadIdx.x;
  if (blockIdx.y == 1) {
    if (blockIdx.x == 0 && tid < 150) bnsum[tid] = 0.f;
    for (int i = blockIdx.x * 256 + tid; i < NN * 160; i += 625 * 256) {
      int r = i / 160, k = i - r * 160;
      float v = 0.f;
      if (k < FI) v = x[(size_t)r * FI + k] * ((deg[r] > 0) ? 1.f : 0.f);
      else if (k < 150) v = x[(size_t)r * FI + k - FI];
      xh[i] = f2bfu(v);
    }
    return;
  }
  __shared__ unsigned short As[32 * 104];   // K padded to 96, stride 104
  __shared__ unsigned short Os[32 * 384];
  int m0 = blockIdx.x * 32;
  for (int i = tid; i < 32 * 104; i += 256) {
    int r = i / 104, k = i - r * 104;
    As[i] = (k < FI) ? f2bfu(x[(size_t)(m0 + r) * FI + k]) : 0;
  }
  __syncthreads();
  int lane = tid & 63, w = tid >> 6;        // wave w: n-cols [w*96, w*96+96)
  int m16 = lane & 15, quad = lane >> 4;
  v4f acc0[6], acc1[6];
#pragma unroll
  for (int nt = 0; nt < 6; ++nt) {
    acc0[nt] = {0.f, 0.f, 0.f, 0.f};
    acc1[nt] = {0.f, 0.f, 0.f, 0.f};
  }
  const unsigned short* arow0 = As + m16 * 104 + quad * 8;
  const unsigned short* arow1 = As + (16 + m16) * 104 + quad * 8;
#pragma unroll
  for (int kb = 0; kb < 3; ++kb) {
    v8s a0 = *(const v8s*)(arow0 + kb * 32);
    v8s a1 = *(const v8s*)(arow1 + kb * 32);
#pragma unroll
    for (int nt = 0; nt < 6; ++nt) {
      v8s bf = *(const v8s*)(BxsL + ((size_t)(kb * 24 + w * 6 + nt) * 64 + lane) * 8);
      acc0[nt] = __builtin_amdgcn_mfma_f32_16x16x32_bf16(a0, bf, acc0[nt], 0, 0, 0);
      acc1[nt] = __builtin_amdgcn_mfma_f32_16x16x32_bf16(a1, bf, acc1[nt], 0, 0, 0);
    }
  }
#pragma unroll
  for (int nt = 0; nt < 6; ++nt) {
    int col = w * 96 + nt * 16 + m16;
#pragma unroll
    for (int r = 0; r < 4; ++r) {
      Os[(quad * 4 + r) * 384 + col] = f2bfu(acc0[nt][r]);
      Os[(16 + quad * 4 + r) * 384 + col] = f2bfu(acc1[nt][r]);
    }
  }
  __syncthreads();
  uint4* dst = (uint4*)(xsb + (size_t)m0 * 384);
  const uint4* src = (const uint4*)Os;
  for (int i = tid; i < 1536; i += 256) dst[i] = src[i];
}

// stats of z = xs[src]+tm[attr]; one node per wave, 64 lanes x 6ch dwordx3 gathers.
__global__ __launch_bounds__(256) void k_aggregate(int n0, int cn,
    const unsigned short* __restrict__ xs, const int2* __restrict__ csr,
    const int* __restrict__ off, const float* __restrict__ inv_deg,
    const unsigned short* __restrict__ tm, unsigned short* __restrict__ aggA) {
  __shared__ unsigned short sm[4 * 1600];
  int tid = threadIdx.x;
  int wv = tid >> 6;                  // node within block (one per wave)
  int lane = tid & 63;
  int rel0 = blockIdx.x * 4;
  int rel = rel0 + wv;
  for (int idx = tid; idx < 400; idx += 256) {   // zero pads (4 rows)
    int h = idx / 100, pp = idx - h * 100;
    int t = pp / 20, cc = pp - t * 20;
    sm[h * 1600 + t * 320 + 300 + cc] = 0;
  }
  if (rel < cn) {
    int n = n0 + rel;
    int c0 = lane * 6;                // cols 375..383 are zero in xs/tm
    int o0 = off[n], o1 = off[n + 1];
    float s[6], q[6], mn[6], mx[6];
#pragma unroll
    for (int j = 0; j < 6; ++j) {
      s[j] = 0.f; q[j] = 0.f; mn[j] = INFINITY; mx[j] = -INFINITY;
    }
    auto proc = [&](uint3 xv, uint3 tv) {
      unsigned xa[3] = {xv.x, xv.y, xv.z};
      unsigned ta[3] = {tv.x, tv.y, tv.z};
#pragma unroll
      for (int j = 0; j < 3; ++j) {
        float z0 = uif(xa[j] << 16) + uif(ta[j] << 16);
        float z1 = uif(xa[j] & 0xffff0000u) + uif(ta[j] & 0xffff0000u);
        s[2 * j] += z0; q[2 * j] = fmaf(z0, z0, q[2 * j]);
        mn[2 * j] = fminf(mn[2 * j], z0); mx[2 * j] = fmaxf(mx[2 * j], z0);
        s[2 * j + 1] += z1; q[2 * j + 1] = fmaf(z1, z1, q[2 * j + 1]);
        mn[2 * j + 1] = fminf(mn[2 * j + 1], z1); mx[2 * j + 1] = fmaxf(mx[2 * j + 1], z1);
      }
    };
    int i = o0;
    for (; i + 8 <= o1; i += 8) {
      int2 e0 = csr[i], e1 = csr[i + 1], e2 = csr[i + 2], e3 = csr[i + 3];
      int2 e4 = csr[i + 4], e5 = csr[i + 5], e6 = csr[i + 6], e7 = csr[i + 7];
      uint3 x0 = *(const uint3*)(xs + (size_t)e0.x * 384 + c0);
      uint3 t0 = *(const uint3*)(tm + (size_t)e0.y * 384 + c0);
      uint3 x1 = *(const uint3*)(xs + (size_t)e1.x * 384 + c0);
      uint3 t1 = *(const uint3*)(tm + (size_t)e1.y * 384 + c0);
      uint3 x2 = *(const uint3*)(xs + (size_t)e2.x * 384 + c0);
      uint3 t2 = *(const uint3*)(tm + (size_t)e2.y * 384 + c0);
      uint3 x3 = *(const uint3*)(xs + (size_t)e3.x * 384 + c0);
      uint3 t3 = *(const uint3*)(tm + (size_t)e3.y * 384 + c0);
      uint3 x4 = *(const uint3*)(xs + (size_t)e4.x * 384 + c0);
      uint3 t4 = *(const uint3*)(tm + (size_t)e4.y * 384 + c0);
      uint3 x5 = *(const uint3*)(xs + (size_t)e5.x * 384 + c0);
      uint3 t5 = *(const uint3*)(tm + (size_t)e5.y * 384 + c0);
      uint3 x6 = *(const uint3*)(xs + (size_t)e6.x * 384 + c0);
      uint3 t6 = *(const uint3*)(tm + (size_t)e6.y * 384 + c0);
      uint3 x7 = *(const uint3*)(xs + (size_t)e7.x * 384 + c0);
      uint3 t7 = *(const uint3*)(tm + (size_t)e7.y * 384 + c0);
      proc(x0, t0); proc(x1, t1); proc(x2, t2); proc(x3, t3);
      proc(x4, t4); proc(x5, t5); proc(x6, t6); proc(x7, t7);
    }
    for (; i + 2 <= o1; i += 2) {
      int2 e0 = csr[i], e1 = csr[i + 1];
      uint3 x0 = *(const uint3*)(xs + (size_t)e0.x * 384 + c0);
      uint3 t0 = *(const uint3*)(tm + (size_t)e0.y * 384 + c0);
      uint3 x1 = *(const uint3*)(xs + (size_t)e1.x * 384 + c0);
      uint3 t1 = *(const uint3*)(tm + (size_t)e1.y * 384 + c0);
      proc(x0, t0); proc(x1, t1);
    }
    if (i < o1) {
      int2 e0 = csr[i];
      uint3 x0 = *(const uint3*)(xs + (size_t)e0.x * 384 + c0);
      uint3 t0 = *(const uint3*)(tm + (size_t)e0.y * 384 + c0);
      proc(x0, t0);
    }
    float inv = inv_deg[n];
    bool empty = (o1 == o0);
    unsigned short* srow = sm + wv * 1600;
#pragma unroll
    for (int j = 0; j < 6; ++j) {
      int c = c0 + j;
      if (c < CH) {
        float me = s[j] * inv;
        float sd = sqrtf(fmaxf(q[j] * inv - me * me, 0.f) + 1e-5f);
        float mnv = empty ? 0.f : mn[j];
        float mxv = empty ? 0.f : mx[j];
        int t = c / 75, ch = c - t * 75;
        unsigned short* bb = srow + t * 320;
        bb[ch] = f2bfu(me);
        bb[75 + ch] = f2bfu(mnv);
        bb[150 + ch] = f2bfu(mxv);
        bb[225 + ch] = f2bfu(sd);
      }
    }
  }
  __syncthreads();
  int nrow = cn - rel0;
  if (nrow > 4) nrow = 4;
  if (nrow > 0) {
    int nu4 = nrow * 200;
    uint4* dst = (uint4*)(aggA + (size_t)rel0 * 1600);
    const uint4* src = (const uint4*)sm;
    for (int idx = tid; idx < nu4; idx += 256) dst[idx] = src[idx];
  }
}

// fused post v5: 10 waves/block, 64 nodes. wave = (tower wv%5, M-half wv/5):
// 2 M-tiles per wave share B fragments; phase2 same split.
__global__ __launch_bounds__(640) void k_post2(int n0, int nend,
    const unsigned short* __restrict__ aggA, const unsigned short* __restrict__ xh,
    const unsigned short* __restrict__ Bp, const float* __restrict__ amp,
    const float* __restrict__ att, const unsigned short* __restrict__ BlinL,
    const float* __restrict__ bcL, float* __restrict__ yout,
    float* __restrict__ bnsum) {
  __shared__ unsigned short zs[64 * 96];   // 12 KB, A-layout [node][k]
  __shared__ float ysum[FI], ysq[FI];
  int tid = threadIdx.x;
  int lane = tid & 63, wv = tid >> 6;      // wv 0..9
  int tw = wv % 5;                         // tower
  int mh = wv / 5;                         // M-half: m tiles {2mh, 2mh+1}
  int m16 = lane & 15, quad = lane >> 4;
  if (tid < FI) { ysum[tid] = 0.f; ysq[tid] = 0.f; }
  for (int i = tid; i < 64 * 21; i += 640) {   // zero k-pad cols 75..95
    int r = i / 21, k = 75 + i - r * 21;
    zs[r * 96 + k] = 0;
  }
  int base = blockIdx.x * 64;
  const unsigned short* bp = Bp + ((size_t)tw * 3 * 15 * 64) * 8 + lane * 8;
  // ---- phase 1: tower tw, 2 M-tiles sharing B ----
  v4f a0[2], a1[2], a2[2];
#pragma unroll
  for (int m = 0; m < 2; ++m) {
    a0[m] = {0.f, 0.f, 0.f, 0.f}; a1[m] = a0[m]; a2[m] = a0[m];
  }
  const unsigned short* arow[2];
  const unsigned short* xrow[2];
#pragma unroll
  for (int m = 0; m < 2; ++m) {
    int relA = base + (mh * 2 + m) * 16 + m16;
    arow[m] = aggA + (size_t)relA * 1600 + tw * 320 + quad * 8;
    xrow[m] = xh + (size_t)(n0 + relA) * 160 + quad * 8;
  }
#pragma unroll
  for (int kb = 0; kb < 15; ++kb) {
    const unsigned short* bb = bp + (size_t)kb * 512;
    v8s b0 = *(const v8s*)(bb);
    v8s b1 = *(const v8s*)(bb + 15 * 512);
    v8s b2 = *(const v8s*)(bb + 30 * 512);
#pragma unroll
    for (int m = 0; m < 2; ++m) {
      v8s av = *(const v8s*)((kb < 10) ? (arow[m] + kb * 32)
                                       : (xrow[m] + (kb - 10) * 32));
      a0[m] = __builtin_amdgcn_mfma_f32_16x16x32_bf16(av, b0, a0[m], 0, 0, 0);
      a1[m] = __builtin_amdgcn_mfma_f32_16x16x32_bf16(av, b1, a1[m], 0, 0, 0);
      a2[m] = __builtin_amdgcn_mfma_f32_16x16x32_bf16(av, b2, a2[m], 0, 0, 0);
    }
  }
  int f = m16;
  if (f < FO) {
#pragma unroll
    for (int m = 0; m < 2; ++m) {
      int relZ = (mh * 2 + m) * 16 + quad * 4;
#pragma unroll
      for (int r = 0; r < 4; ++r) {
        int nd = n0 + base + relZ + r;
        int ndc = (nd < NN) ? nd : (NN - 1);
        float zz = a0[m][r] + amp[ndc] * a1[m][r] + att[ndc] * a2[m][r];
        zs[(relZ + r) * 96 + tw * FO + f] = f2bfu(zz);
      }
    }
  }
  __syncthreads();
  // ---- phase 2: y cols [tw*16, tw*16+16) for 2 M-tiles ----
  v4f acc2[2];
#pragma unroll
  for (int m = 0; m < 2; ++m) acc2[m] = {0.f, 0.f, 0.f, 0.f};
#pragma unroll
  for (int kb = 0; kb < 3; ++kb) {
    v8s bl = *(const v8s*)(BlinL + ((size_t)(kb * 5 + tw) * 64 + lane) * 8);
#pragma unroll
    for (int m = 0; m < 2; ++m) {
      v8s av = *(const v8s*)(zs + ((mh * 2 + m) * 16 + m16) * 96 + quad * 8 + kb * 32);
      acc2[m] = __builtin_amdgcn_mfma_f32_16x16x32_bf16(av, bl, acc2[m], 0, 0, 0);
    }
  }
  int fcol = tw * 16 + m16;
  if (fcol < FI) {
    float bcf = bcL[fcol];
#pragma unroll
    for (int m = 0; m < 2; ++m) {
      int nb = n0 + base + (mh * 2 + m) * 16 + quad * 4;
#pragma unroll
      for (int r = 0; r < 4; ++r) {
        int n = nb + r;
        if (n < nend) {
          float v = acc2[m][r] + bcf;
          yout[(size_t)n * FI + fcol] = v;
          atomicAdd(&ysum[fcol], v);
          atomicAdd(&ysq[fcol], v * v);
        }
      }
    }
  }
  __syncthreads();
  if (tid < FI) {
    atomicAdd(&bnsum[tid], ysum[tid]);
    atomicAdd(&bnsum[FI + tid], ysq[tid]);
  }
}

// BN finalize+apply; dopool==0: also zero pooled for next layer; dopool==1: pool.
__global__ __launch_bounds__(256) void k_bnfinapply(const float* __restrict__ y,
    const float* __restrict__ bnsum, const float* __restrict__ gamL,
    const float* __restrict__ betL, float* __restrict__ xo,
    const int* __restrict__ batch, float* __restrict__ pooled, int dopool) {
  __shared__ float sc[150];
  int tid = threadIdx.x;
  if (tid < FI) {
    float mu = bnsum[tid] / (float)NN;
    float var = bnsum[FI + tid] / (float)NN - mu * mu;
    float scl = gamL[tid] * rsqrtf(var + 1e-5f);
    sc[tid] = scl;
    sc[FI + tid] = betL[tid] - mu * scl;
  }
  if (!dopool) {
    for (int i = blockIdx.x * 256 + tid; i < NG * FI; i += gridDim.x * 256)
      pooled[i] = 0.f;
  }
  __syncthreads();
  int stride = gridDim.x * 256;
  for (int i = blockIdx.x * 256 + tid; i < NN * FI; i += stride) {
    int n = i / FI, f = i - n * FI;
    float v = fmaxf(fmaf(y[i], sc[f], sc[FI + f]), 0.f);
    xo[i] = v;
    if (dopool) atomicAdd(&pooled[batch[n] * FI + f], v);
  }
}

__global__ void k_head(const float* __restrict__ pooled, const float* __restrict__ W1,
                       const float* __restrict__ b1, const float* __restrict__ W2,
                       const float* __restrict__ b2, const float* __restrict__ W3,
                       const float* __restrict__ b3, float* __restrict__ out) {
  __shared__ float p[FI], h1[50], h2[25];
  int g = blockIdx.x, t = threadIdx.x;
  for (int i = t; i < FI; i += 64) p[i] = pooled[g * FI + i];
  __syncthreads();
  if (t < 50) {
    float a = b1[t];
    for (int j = 0; j < FI; ++j) a = fmaf(p[j], W1[j * 50 + t], a);
    h1[t] = fmaxf(a, 0.f);
  }
  __syncthreads();
  if (t < 25) {
    float a = b2[t];
    for (int j = 0; j < 50; ++j) a = fmaf(h1[j], W2[j * 25 + t], a);
    h2[t] = fmaxf(a, 0.f);
  }
  __syncthreads();
  if (t == 0) {
    float a = b3[0];
    for (int j = 0; j < 25; ++j) a = fmaf(h2[j], W3[j], a);
    out[g] = a;
  }
}

extern "C" void kernel_launch(void* const* d_in, const int* in_sizes, int n_in,
                              void* d_out, int out_size, void* d_ws, size_t ws_size,
                              hipStream_t stream) {
  const int* x_idx = (const int*)d_in[0];
  const int* eidx  = (const int*)d_in[1];
  const int* srcp  = eidx;
  const int* dstp  = eidx + NE;
  const int* eattr = (const int*)d_in[2];
  const int* batch = (const int*)d_in[3];
  const float* node_emb = (const float*)d_in[4];
  const float* edge_emb = (const float*)d_in[5];
  const float* W_edge = (const float*)d_in[6];
  const float* b_edge = (const float*)d_in[7];
  const float* W_pre  = (const float*)d_in[8];
  const float* b_pre  = (const float*)d_in[9];
  const float* W_post = (const float*)d_in[10];
  const float* b_post = (const float*)d_in[11];
  const float* W_lin  = (const float*)d_in[12];
  const float* b_lin  = (const float*)d_in[13];
  const float* gam = (const float*)d_in[14];
  const float* bet = (const float*)d_in[15];
  const float* W1 = (const float*)d_in[16];
  const float* b1 = (const float*)d_in[17];
  const float* W2 = (const float*)d_in[18];
  const float* b2 = (const float*)d_in[19];
  const float* W3 = (const float*)d_in[20];
  const float* b3 = (const float*)d_in[21];

  char* p = (char*)d_ws;
  auto alloc = [&](size_t b) -> char* {
    char* r = p;
    p += (b + 255) & ~(size_t)255;
    return r;
  };
  float* x_a   = (float*)alloc((size_t)NN * FI * 4);
  float* x_b   = (float*)alloc((size_t)NN * FI * 4);
  unsigned short* xs_bf = (unsigned short*)alloc((size_t)NN * 384 * 2);
  float* z     = (float*)alloc((size_t)NN * FI * 4);
  unsigned short* xh = (unsigned short*)alloc((size_t)(NN + 64) * 160 * 2);
  float* te    = (float*)alloc(2 * 100 * FI * 4);
  unsigned short* tm_bf = (unsigned short*)alloc((size_t)2 * 100 * 384 * 2);
  float* WAs   = (float*)alloc((size_t)2 * FI * CH * 4);
  float* V     = (float*)alloc((size_t)2 * NT * 3 * FI * 16 * 4);
  unsigned short* Bpk = (unsigned short*)alloc((size_t)230400 * 2);
  unsigned short* Bxs = (unsigned short*)alloc((size_t)73728 * 2);
  unsigned short* Blin = (unsigned short*)alloc((size_t)15360 * 2);
  float* bc    = (float*)alloc(2 * 76 * 4);
  float* ampv  = (float*)alloc((size_t)NN * 4);
  float* attv  = (float*)alloc((size_t)NN * 4);
  float* invv  = (float*)alloc((size_t)NN * 4);
  float* avglog = (float*)alloc(256);
  float* bnsum = (float*)alloc(2 * FI * 4);
  float* pooled = (float*)alloc((size_t)NG * FI * 4);
  int* deg = (int*)alloc((size_t)NN * 4);
  int* off = (int*)alloc((size_t)(NN + 1) * 4);
  int* cur = (int*)alloc((size_t)NN * 4);
  int2* csr = (int2*)alloc((size_t)NE * 8);
  size_t used = (size_t)(p - (char*)d_ws);
  int chunkN = NN;
  while (chunkN > 2500 &&
         used + (size_t)((chunkN + 63) & ~63) * 1600 * 2 + (1 << 20) > ws_size)
    chunkN >>= 1;
  int rows = (chunkN + 63) & ~63;
  unsigned short* aggA = (unsigned short*)alloc((size_t)rows * 1600 * 2);

  hipMemsetAsync(deg, 0, (size_t)NN * 4, stream);

  k_mega1<<<7562, 256, 0, stream>>>(x_idx, node_emb, x_a, dstp, deg,
                                    edge_emb, W_edge, b_edge, te,
                                    W_pre, WAs, W_post, V,
                                    b_post, W_lin, b_lin, bc);
  k_mega2<<<389, 1024, 0, stream>>>(deg, off, cur, avglog,
                                    te, W_pre, b_pre, tm_bf, W_post, V, Bpk,
                                    WAs, Bxs, W_lin, Blin);
  k_mega3<<<1329, 256, 0, stream>>>(srcp, dstp, eattr, cur, csr,
                                    deg, avglog, ampv, attv, invv);

  for (int l = 0; l < 2; ++l) {
    const float* xin = (l == 0) ? x_a : x_b;
    float* xout = (l == 0) ? x_b : x_a;
    k_gemm_xs<<<dim3(625, 2), 256, 0, stream>>>(xin, Bxs + (size_t)l * 36864,
                                                xs_bf, deg, xh, bnsum);
    for (int n0 = 0; n0 < NN; n0 += chunkN) {
      int cn = (NN - n0 < chunkN) ? (NN - n0) : chunkN;
      k_aggregate<<<(cn + 3) / 4, 256, 0, stream>>>(n0, cn, xs_bf, csr, off, invv,
                                                    tm_bf + (size_t)l * 100 * 384, aggA);
      k_post2<<<(cn + 63) / 64, 640, 0, stream>>>(
          n0, n0 + cn, aggA, xh, Bpk + (size_t)l * 115200, ampv, attv,
          Blin + (size_t)l * 7680, bc + l * 76, z, bnsum);
    }
    k_bnfinapply<<<1250, 256, 0, stream>>>(z, bnsum, gam + l * FI, bet + l * FI,
                                           xout, batch, pooled, (l == 1) ? 1 : 0);
  }

  k_head<<<NG, 64, 0, stream>>>(pooled, W1, b1, W2, b2, W3, b3, (float*)d_out);
}

// Round 17
// 432.271 us; speedup vs baseline: 1.0445x; 1.0445x over previous
//
#include <hip/hip_runtime.h>
#include <hip/hip_bf16.h>
#include <math.h>

#define NN 20000
#define NE 320000
#define NG 200
#define FI 75
#define NT 5
#define FO 15
#define CH 375     // NT*FI
#define PI 975
#define SMS 1608   // LDS stats row stride (ushorts): 16B-aligned, 2-way-free banks

typedef __attribute__((ext_vector_type(8))) short v8s;
typedef __attribute__((ext_vector_type(4))) float v4f;

__device__ __forceinline__ unsigned short f2bfu(float v) {
  __hip_bfloat16 h = __float2bfloat16(v);
  return *reinterpret_cast<unsigned short*>(&h);
}
__device__ __forceinline__ float uif(unsigned u) { return __uint_as_float(u); }

// ================= prep mega kernels =================
// mega1 (256 thr): gather_x | count | table_e | repack_WAs | make_V | bias_comb
__global__ __launch_bounds__(256) void k_mega1(
    const int* __restrict__ xidx, const float* __restrict__ emb, float* __restrict__ x,
    const int* __restrict__ dstp, int* __restrict__ deg,
    const float* __restrict__ eemb, const float* __restrict__ W_edge,
    const float* __restrict__ b_edge, float* __restrict__ te,
    const float* __restrict__ W_pre, float* __restrict__ WAs,
    const float* __restrict__ W_post, float* __restrict__ V,
    const float* __restrict__ b_post, const float* __restrict__ W_lin,
    const float* __restrict__ b_lin, float* __restrict__ bc) {
  __shared__ float S[FI * 16];
  int b = blockIdx.x, tid = threadIdx.x;
  if (b < 5860) {                       // gather_x
    int i = b * 256 + tid;
    if (i < NN * FI) {
      int n = i / FI, f = i - n * FI;
      x[i] = emb[xidx[n] * FI + f];
    }
  } else if (b < 7110) {                // count
    int e = (b - 5860) * 256 + tid;
    if (e < NE) atomicAdd(&deg[dstp[e]], 1);
  } else if (b < 7310) {                // table_e
    int la = b - 7110;
    int l = la / 100, a = la - l * 100;
    int f = tid;
    if (f < FI) {
      float acc = b_edge[l * FI + f];
      for (int j = 0; j < 50; ++j)
        acc = fmaf(eemb[a * 50 + j], W_edge[(l * 50 + j) * FI + f], acc);
      te[la * FI + f] = acc;
    }
  } else if (b < 7530) {                // repack_WAs
    int i = (b - 7310) * 256 + tid;
    if (i < 2 * FI * CH) {
      int c = i % CH;
      int k = (i / CH) % FI;
      int l = i / (CH * FI);
      int t = c / FI, f = c - t * FI;
      WAs[i] = W_pre[((size_t)(l * NT + t) * 225 + FI + k) * FI + f];
    }
  } else if (b < 7560) {                // make_V
    int bid = b - 7530;                 // (l*5+t)*3+g
    int g = bid % 3;
    int lt = bid / 3;
    for (int idx = tid; idx < FI * 16; idx += 256) {
      int q = idx >> 4, f = idx & 15;
      float v = 0.f;
      if (f < FO) {
        const float* wb = W_post + (size_t)lt * PI * FO;
        int rowb = FI + g * 300 + q;
        v = wb[rowb * FO + f] + wb[(rowb + FI) * FO + f] + wb[(rowb + 2 * FI) * FO + f];
      }
      S[idx] = v;
    }
    __syncthreads();
    for (int idx = tid; idx < FI * 16; idx += 256) {
      int j = idx >> 4, f = idx & 15;
      float acc = 0.f;
      const float* wr = W_pre + ((size_t)lt * 225 + j) * FI;
      for (int q = 0; q < FI; ++q) acc = fmaf(wr[q], S[q * 16 + f], acc);
      V[((size_t)bid * FI + j) * 16 + f] = acc;
    }
  } else {                              // bias_comb
    int l = b - 7560;
    int g = tid;
    if (g < FI) {
      float acc = b_lin[l * FI + g];
      for (int j = 0; j < FI; ++j)
        acc = fmaf(b_post[l * FI + j], W_lin[(l * FI + j) * FI + g], acc);
      bc[l * 76 + g] = acc;
    }
  }
}

// mega2 (1024 thr): scan | logsum | tbl_m | pack_B | pack_Bxs | pack_Blin
__global__ __launch_bounds__(1024) void k_mega2(
    const int* __restrict__ deg, int* __restrict__ off, int* __restrict__ cur,
    float* __restrict__ avglog,
    const float* __restrict__ te, const float* __restrict__ W_pre,
    const float* __restrict__ b_pre, unsigned short* __restrict__ tm,
    const float* __restrict__ W_post, const float* __restrict__ V,
    unsigned short* __restrict__ Bp,
    const float* __restrict__ WAs, unsigned short* __restrict__ Bxs,
    const float* __restrict__ W_lin, unsigned short* __restrict__ Blin) {
  __shared__ float red[1024];
  int b = blockIdx.x, t = threadIdx.x;
  if (b == 0) {                         // scan: 1024 x 20
    int* wsum = (int*)red;
    int base = t * 20;
    int loc[20];
    int s = 0;
#pragma unroll
    for (int j = 0; j < 20; ++j) {
      int i = base + j;
      int v = (i < NN) ? deg[i] : 0;
      loc[j] = s;
      s += v;
    }
    int lane = t & 63, w = t >> 6;
    int inc = s;
    for (int o = 1; o < 64; o <<= 1) {
      int u = __shfl_up(inc, o, 64);
      if (lane >= o) inc += u;
    }
    if (lane == 63) wsum[w] = inc;
    __syncthreads();
    if (t == 0) {
      int a = 0;
#pragma unroll
      for (int k = 0; k < 16; ++k) { int v = wsum[k]; wsum[k] = a; a += v; }
    }
    __syncthreads();
    int tex = wsum[w] + inc - s;
#pragma unroll
    for (int j = 0; j < 20; ++j) {
      int i = base + j;
      if (i < NN) { int e = tex + loc[j]; off[i] = e; cur[i] = e; }
    }
    if (t == 1023) off[NN] = tex + s;
  } else if (b == 1) {                  // logsum
    float s = 0.f;
    for (int i = t; i < NN; i += 1024) s += logf((float)deg[i] + 1.f);
    red[t] = s;
    __syncthreads();
    for (int o = 512; o > 0; o >>= 1) {
      if (t < o) red[t] += red[t + o];
      __syncthreads();
    }
    if (t == 0) avglog[0] = red[0] / (float)NN;
  } else if (b < 77) {                  // tbl_m flat: 2*100*384
    int idx = (b - 2) * 1024 + t;
    if (idx < 76800) {
      int la = idx / 384, c = idx - la * 384;
      int l = la / 100;
      float acc = 0.f;
      if (c < CH) {
        int tt = c / FI, f = c - tt * FI;
        acc = b_pre[(l * NT + tt) * FI + f];
        const float* ter = te + la * FI;
        for (int k = 0; k < FI; ++k)
          acc = fmaf(ter[k], W_pre[((size_t)(l * NT + tt) * 225 + 150 + k) * FI + f], acc);
      }
      tm[(size_t)la * 384 + c] = f2bfu(acc);
    }
  } else if (b < 302) {                 // pack_B (post MFMA weights)
    int i = (b - 77) * 1024 + t;
    if (i < 230400) {
      int j = i & 7;
      int lane = (i >> 3) & 63;
      int rem = i >> 9;
      int kb = rem % 15; rem /= 15;
      int g = rem % 3; rem /= 3;
      int tt = rem % 5;
      int l = rem / 5;
      int k = kb * 32 + (lane >> 4) * 8 + j;
      int f = lane & 15;
      float w = 0.f;
      if (f < FO) {
        int lt = l * NT + tt;
        if (k < 300) {
          int a = k / 75, ch = k - a * 75;
          w = W_post[((size_t)lt * PI + FI + g * 300 + a * 75 + ch) * FO + f];
        } else if (k >= 320 && k < 395) {
          w = V[(((size_t)(lt * 3 + g)) * FI + (k - 320)) * 16 + f];
        } else if (k >= 395 && k < 470 && g == 0) {
          w = W_post[((size_t)lt * PI + (k - 395)) * FO + f];
        }
      }
      Bp[i] = f2bfu(w);
    }
  } else if (b < 374) {                 // pack_Bxs (xs MFMA weights), 73728 elems
    int i = (b - 302) * 1024 + t;
    if (i < 73728) {
      int j = i & 7;
      int lane = (i >> 3) & 63;
      int rem = i >> 9;                 // 0..143
      int nt = rem % 24; rem /= 24;
      int kb = rem % 3;
      int l = rem / 3;
      int k = kb * 32 + (lane >> 4) * 8 + j;
      int n = nt * 16 + (lane & 15);
      float w = 0.f;
      if (k < FI && n < CH) w = WAs[(size_t)l * FI * CH + k * CH + n];
      Bxs[i] = f2bfu(w);
    }
  } else {                              // pack_Blin (W_lin MFMA weights), 15360 elems
    int i = (b - 374) * 1024 + t;
    if (i < 15360) {
      int j = i & 7;
      int lane = (i >> 3) & 63;
      int rem = i >> 9;                 // 0..29
      int nt = rem % 5; rem /= 5;
      int kb = rem % 3;
      int l = rem / 3;
      int k = kb * 32 + (lane >> 4) * 8 + j;
      int f = nt * 16 + (lane & 15);
      float w = 0.f;
      if (k < FI && f < FI) w = W_lin[(size_t)l * FI * FI + k * FI + f];
      Blin[i] = f2bfu(w);
    }
  }
}

// mega3 (256 thr): fill | scalers
__global__ __launch_bounds__(256) void k_mega3(
    const int* __restrict__ srcp, const int* __restrict__ dstp,
    const int* __restrict__ attr, int* __restrict__ cur, int2* __restrict__ csr,
    const int* __restrict__ deg, const float* __restrict__ avglog,
    float* __restrict__ amp, float* __restrict__ att, float* __restrict__ inv) {
  int b = blockIdx.x, t = threadIdx.x;
  if (b < 1250) {
    int e = b * 256 + t;
    if (e < NE) {
      int pos = atomicAdd(&cur[dstp[e]], 1);
      csr[pos] = make_int2(srcp[e], attr[e]);
    }
  } else {
    int i = (b - 1250) * 256 + t;
    if (i < NN) {
      float dc = fmaxf((float)deg[i], 1.f);
      float ld = logf(dc + 1.f);
      float av = avglog[0];
      amp[i] = ld / av;
      att[i] = av / ld;
      inv[i] = 1.f / dc;
    }
  }
}

// ================= per-layer =================
// y==0: xs_bf[n,0:384] = x@W_pre_src via MFMA.  y==1: build xh + zero bnsum.
__global__ __launch_bounds__(256) void k_gemm_xs(const float* __restrict__ x,
                                                 const unsigned short* __restrict__ BxsL,
                                                 unsigned short* __restrict__ xsb,
                                                 const int* __restrict__ deg,
                                                 unsigned short* __restrict__ xh,
                                                 float* __restrict__ bnsum) {
  int tid = threadIdx.x;
  if (blockIdx.y == 1) {
    if (blockIdx.x == 0 && tid < 150) bnsum[tid] = 0.f;
    for (int i = blockIdx.x * 256 + tid; i < NN * 160; i += 625 * 256) {
      int r = i / 160, k = i - r * 160;
      float v = 0.f;
      if (k < FI) v = x[(size_t)r * FI + k] * ((deg[r] > 0) ? 1.f : 0.f);
      else if (k < 150) v = x[(size_t)r * FI + k - FI];
      xh[i] = f2bfu(v);
    }
    return;
  }
  __shared__ unsigned short As[32 * 104];   // K padded to 96, stride 104
  __shared__ unsigned short Os[32 * 384];
  int m0 = blockIdx.x * 32;
  for (int i = tid; i < 32 * 104; i += 256) {
    int r = i / 104, k = i - r * 104;
    As[i] = (k < FI) ? f2bfu(x[(size_t)(m0 + r) * FI + k]) : 0;
  }
  __syncthreads();
  int lane = tid & 63, w = tid >> 6;        // wave w: n-cols [w*96, w*96+96)
  int m16 = lane & 15, quad = lane >> 4;
  v4f acc0[6], acc1[6];
#pragma unroll
  for (int nt = 0; nt < 6; ++nt) {
    acc0[nt] = {0.f, 0.f, 0.f, 0.f};
    acc1[nt] = {0.f, 0.f, 0.f, 0.f};
  }
  const unsigned short* arow0 = As + m16 * 104 + quad * 8;
  const unsigned short* arow1 = As + (16 + m16) * 104 + quad * 8;
#pragma unroll
  for (int kb = 0; kb < 3; ++kb) {
    v8s a0 = *(const v8s*)(arow0 + kb * 32);
    v8s a1 = *(const v8s*)(arow1 + kb * 32);
#pragma unroll
    for (int nt = 0; nt < 6; ++nt) {
      v8s bf = *(const v8s*)(BxsL + ((size_t)(kb * 24 + w * 6 + nt) * 64 + lane) * 8);
      acc0[nt] = __builtin_amdgcn_mfma_f32_16x16x32_bf16(a0, bf, acc0[nt], 0, 0, 0);
      acc1[nt] = __builtin_amdgcn_mfma_f32_16x16x32_bf16(a1, bf, acc1[nt], 0, 0, 0);
    }
  }
#pragma unroll
  for (int nt = 0; nt < 6; ++nt) {
    int col = w * 96 + nt * 16 + m16;
#pragma unroll
    for (int r = 0; r < 4; ++r) {
      Os[(quad * 4 + r) * 384 + col] = f2bfu(acc0[nt][r]);
      Os[(16 + quad * 4 + r) * 384 + col] = f2bfu(acc1[nt][r]);
    }
  }
  __syncthreads();
  uint4* dst = (uint4*)(xsb + (size_t)m0 * 384);
  const uint4* src = (const uint4*)Os;
  for (int i = tid; i < 1536; i += 256) dst[i] = src[i];
}

// fused aggregate+post: block = 1024 thr (16 waves) = 16 nodes, no aggA round-trip.
// phase1: wave wv gathers node blk*16+wv (lane owns 6 ch, uint3); stats bf16 -> LDS.
// phase2: waves 0..4 = towers, A from LDS, 15 kb MFMAs x3 groups -> z bf16 LDS.
// phase3: waves 0..4: y cols [t*16,t*16+16) = z@W_lin + bc -> global + BN partials.
__global__ __launch_bounds__(1024) void k_aggpost(
    const unsigned short* __restrict__ xs, const int2* __restrict__ csr,
    const int* __restrict__ off, const float* __restrict__ inv_deg,
    const unsigned short* __restrict__ tm, const unsigned short* __restrict__ xh,
    const unsigned short* __restrict__ Bp, const float* __restrict__ amp,
    const float* __restrict__ att, const unsigned short* __restrict__ BlinL,
    const float* __restrict__ bcL, float* __restrict__ yout,
    float* __restrict__ bnsum) {
  __shared__ __align__(16) unsigned short sm[16 * SMS];   // ~50.3 KB
  __shared__ __align__(16) unsigned short zs[16 * 96];    // 3 KB
  __shared__ float ysum[FI], ysq[FI];
  int tid = threadIdx.x;
  int wv = tid >> 6, lane = tid & 63;
  int rel0 = blockIdx.x * 16;
  int n = rel0 + wv;
  if (tid < FI) { ysum[tid] = 0.f; ysq[tid] = 0.f; }
  for (int idx = tid; idx < 1600; idx += 1024) {   // zero per-tower pads (16 rows)
    int h = idx / 100, pp = idx - h * 100;
    int t = pp / 20, cc = pp - t * 20;
    sm[h * SMS + t * 320 + 300 + cc] = 0;
  }
  for (int i = tid; i < 16 * 21; i += 1024) {      // zero zs k-pad cols 75..95
    int r = i / 21, k = 75 + i - r * 21;
    zs[r * 96 + k] = 0;
  }
  if (n < NN) {
    int c0 = lane * 6;                // cols 375..383 are zero in xs/tm
    int o0 = off[n], o1 = off[n + 1];
    float s[6], q[6], mn[6], mx[6];
#pragma unroll
    for (int j = 0; j < 6; ++j) {
      s[j] = 0.f; q[j] = 0.f; mn[j] = INFINITY; mx[j] = -INFINITY;
    }
    auto proc = [&](uint3 xv, uint3 tv) {
      unsigned xa[3] = {xv.x, xv.y, xv.z};
      unsigned ta[3] = {tv.x, tv.y, tv.z};
#pragma unroll
      for (int j = 0; j < 3; ++j) {
        float z0 = uif(xa[j] << 16) + uif(ta[j] << 16);
        float z1 = uif(xa[j] & 0xffff0000u) + uif(ta[j] & 0xffff0000u);
        s[2 * j] += z0; q[2 * j] = fmaf(z0, z0, q[2 * j]);
        mn[2 * j] = fminf(mn[2 * j], z0); mx[2 * j] = fmaxf(mx[2 * j], z0);
        s[2 * j + 1] += z1; q[2 * j + 1] = fmaf(z1, z1, q[2 * j + 1]);
        mn[2 * j + 1] = fminf(mn[2 * j + 1], z1); mx[2 * j + 1] = fmaxf(mx[2 * j + 1], z1);
      }
    };
    int i = o0;
    for (; i + 4 <= o1; i += 4) {
      int2 e0 = csr[i], e1 = csr[i + 1], e2 = csr[i + 2], e3 = csr[i + 3];
      uint3 x0 = *(const uint3*)(xs + (size_t)e0.x * 384 + c0);
      uint3 t0 = *(const uint3*)(tm + (size_t)e0.y * 384 + c0);
      uint3 x1 = *(const uint3*)(xs + (size_t)e1.x * 384 + c0);
      uint3 t1 = *(const uint3*)(tm + (size_t)e1.y * 384 + c0);
      uint3 x2 = *(const uint3*)(xs + (size_t)e2.x * 384 + c0);
      uint3 t2 = *(const uint3*)(tm + (size_t)e2.y * 384 + c0);
      uint3 x3 = *(const uint3*)(xs + (size_t)e3.x * 384 + c0);
      uint3 t3 = *(const uint3*)(tm + (size_t)e3.y * 384 + c0);
      proc(x0, t0); proc(x1, t1); proc(x2, t2); proc(x3, t3);
    }
    for (; i < o1; ++i) {
      int2 e0 = csr[i];
      uint3 x0 = *(const uint3*)(xs + (size_t)e0.x * 384 + c0);
      uint3 t0 = *(const uint3*)(tm + (size_t)e0.y * 384 + c0);
      proc(x0, t0);
    }
    float inv = inv_deg[n];
    bool empty = (o1 == o0);
    unsigned short* srow = sm + wv * SMS;
#pragma unroll
    for (int j = 0; j < 6; ++j) {
      int c = c0 + j;
      if (c < CH) {
        float me = s[j] * inv;
        float sd = sqrtf(fmaxf(q[j] * inv - me * me, 0.f) + 1e-5f);
        float mnv = empty ? 0.f : mn[j];
        float mxv = empty ? 0.f : mx[j];
        int t = c / 75, ch = c - t * 75;
        unsigned short* bb = srow + t * 320;
        bb[ch] = f2bfu(me);
        bb[75 + ch] = f2bfu(mnv);
        bb[150 + ch] = f2bfu(mxv);
        bb[225 + ch] = f2bfu(sd);
      }
    }
  } else {
    uint* rowz = (uint*)(sm + wv * SMS);
    for (int idx2 = lane; idx2 < SMS / 2; idx2 += 64) rowz[idx2] = 0;
  }
  __syncthreads();
  // ---- phase 2: tower MFMA from LDS ----
  int m16 = lane & 15, quad = lane >> 4;
  if (wv < NT) {
    int tw = wv;
    const unsigned short* arow = sm + m16 * SMS + tw * 320 + quad * 8;
    const unsigned short* xrow = xh + (size_t)(rel0 + m16) * 160 + quad * 8;
    const unsigned short* bp = Bp + ((size_t)tw * 3 * 15 * 64) * 8 + lane * 8;
    v4f a0 = {0.f, 0.f, 0.f, 0.f}, a1 = a0, a2 = a0;
#pragma unroll
    for (int kb = 0; kb < 15; ++kb) {
      v8s av = *(const v8s*)((kb < 10) ? (arow + kb * 32) : (xrow + (kb - 10) * 32));
      const unsigned short* bb = bp + (size_t)kb * 512;
      v8s b0 = *(const v8s*)(bb);
      v8s b1 = *(const v8s*)(bb + 15 * 512);
      v8s b2 = *(const v8s*)(bb + 30 * 512);
      a0 = __builtin_amdgcn_mfma_f32_16x16x32_bf16(av, b0, a0, 0, 0, 0);
      a1 = __builtin_amdgcn_mfma_f32_16x16x32_bf16(av, b1, a1, 0, 0, 0);
      a2 = __builtin_amdgcn_mfma_f32_16x16x32_bf16(av, b2, a2, 0, 0, 0);
    }
    int f = m16;
    if (f < FO) {
      int relZ = quad * 4;
#pragma unroll
      for (int r = 0; r < 4; ++r) {
        int nd = rel0 + relZ + r;
        int ndc = (nd < NN) ? nd : (NN - 1);
        float zz = a0[r] + amp[ndc] * a1[r] + att[ndc] * a2[r];
        zs[(relZ + r) * 96 + tw * FO + f] = f2bfu(zz);
      }
    }
  }
  __syncthreads();
  // ---- phase 3: y cols [tw*16, tw*16+16) ----
  if (wv < NT) {
    int tw = wv;
    v4f acc2 = {0.f, 0.f, 0.f, 0.f};
#pragma unroll
    for (int kb = 0; kb < 3; ++kb) {
      v8s av = *(const v8s*)(zs + m16 * 96 + quad * 8 + kb * 32);
      v8s bl = *(const v8s*)(BlinL + ((size_t)(kb * 5 + tw) * 64 + lane) * 8);
      acc2 = __builtin_amdgcn_mfma_f32_16x16x32_bf16(av, bl, acc2, 0, 0, 0);
    }
    int fcol = tw * 16 + m16;
    if (fcol < FI) {
      float bcf = bcL[fcol];
      int nb = rel0 + quad * 4;
#pragma unroll
      for (int r = 0; r < 4; ++r) {
        int nd = nb + r;
        if (nd < NN) {
          float v = acc2[r] + bcf;
          yout[(size_t)nd * FI + fcol] = v;
          atomicAdd(&ysum[fcol], v);
          atomicAdd(&ysq[fcol], v * v);
        }
      }
    }
  }
  __syncthreads();
  if (tid < FI) {
    atomicAdd(&bnsum[tid], ysum[tid]);
    atomicAdd(&bnsum[FI + tid], ysq[tid]);
  }
}

// BN finalize+apply; dopool==0: also zero pooled for next layer; dopool==1: pool.
__global__ __launch_bounds__(256) void k_bnfinapply(const float* __restrict__ y,
    const float* __restrict__ bnsum, const float* __restrict__ gamL,
    const float* __restrict__ betL, float* __restrict__ xo,
    const int* __restrict__ batch, float* __restrict__ pooled, int dopool) {
  __shared__ float sc[150];
  int tid = threadIdx.x;
  if (tid < FI) {
    float mu = bnsum[tid] / (float)NN;
    float var = bnsum[FI + tid] / (float)NN - mu * mu;
    float scl = gamL[tid] * rsqrtf(var + 1e-5f);
    sc[tid] = scl;
    sc[FI + tid] = betL[tid] - mu * scl;
  }
  if (!dopool) {
    for (int i = blockIdx.x * 256 + tid; i < NG * FI; i += gridDim.x * 256)
      pooled[i] = 0.f;
  }
  __syncthreads();
  int stride = gridDim.x * 256;
  for (int i = blockIdx.x * 256 + tid; i < NN * FI; i += stride) {
    int n = i / FI, f = i - n * FI;
    float v = fmaxf(fmaf(y[i], sc[f], sc[FI + f]), 0.f);
    xo[i] = v;
    if (dopool) atomicAdd(&pooled[batch[n] * FI + f], v);
  }
}

__global__ void k_head(const float* __restrict__ pooled, const float* __restrict__ W1,
                       const float* __restrict__ b1, const float* __restrict__ W2,
                       const float* __restrict__ b2, const float* __restrict__ W3,
                       const float* __restrict__ b3, float* __restrict__ out) {
  __shared__ float p[FI], h1[50], h2[25];
  int g = blockIdx.x, t = threadIdx.x;
  for (int i = t; i < FI; i += 64) p[i] = pooled[g * FI + i];
  __syncthreads();
  if (t < 50) {
    float a = b1[t];
    for (int j = 0; j < FI; ++j) a = fmaf(p[j], W1[j * 50 + t], a);
    h1[t] = fmaxf(a, 0.f);
  }
  __syncthreads();
  if (t < 25) {
    float a = b2[t];
    for (int j = 0; j < 50; ++j) a = fmaf(h1[j], W2[j * 25 + t], a);
    h2[t] = fmaxf(a, 0.f);
  }
  __syncthreads();
  if (t == 0) {
    float a = b3[0];
    for (int j = 0; j < 25; ++j) a = fmaf(h2[j], W3[j], a);
    out[g] = a;
  }
}

extern "C" void kernel_launch(void* const* d_in, const int* in_sizes, int n_in,
                              void* d_out, int out_size, void* d_ws, size_t ws_size,
                              hipStream_t stream) {
  const int* x_idx = (const int*)d_in[0];
  const int* eidx  = (const int*)d_in[1];
  const int* srcp  = eidx;
  const int* dstp  = eidx + NE;
  const int* eattr = (const int*)d_in[2];
  const int* batch = (const int*)d_in[3];
  const float* node_emb = (const float*)d_in[4];
  const float* edge_emb = (const float*)d_in[5];
  const float* W_edge = (const float*)d_in[6];
  const float* b_edge = (const float*)d_in[7];
  const float* W_pre  = (const float*)d_in[8];
  const float* b_pre  = (const float*)d_in[9];
  const float* W_post = (const float*)d_in[10];
  const float* b_post = (const float*)d_in[11];
  const float* W_lin  = (const float*)d_in[12];
  const float* b_lin  = (const float*)d_in[13];
  const float* gam = (const float*)d_in[14];
  const float* bet = (const float*)d_in[15];
  const float* W1 = (const float*)d_in[16];
  const float* b1 = (const float*)d_in[17];
  const float* W2 = (const float*)d_in[18];
  const float* b2 = (const float*)d_in[19];
  const float* W3 = (const float*)d_in[20];
  const float* b3 = (const float*)d_in[21];

  char* p = (char*)d_ws;
  auto alloc = [&](size_t b) -> char* {
    char* r = p;
    p += (b + 255) & ~(size_t)255;
    return r;
  };
  float* x_a   = (float*)alloc((size_t)NN * FI * 4);
  float* x_b   = (float*)alloc((size_t)NN * FI * 4);
  unsigned short* xs_bf = (unsigned short*)alloc((size_t)NN * 384 * 2);
  float* z     = (float*)alloc((size_t)NN * FI * 4);
  unsigned short* xh = (unsigned short*)alloc((size_t)(NN + 64) * 160 * 2);
  float* te    = (float*)alloc(2 * 100 * FI * 4);
  unsigned short* tm_bf = (unsigned short*)alloc((size_t)2 * 100 * 384 * 2);
  float* WAs   = (float*)alloc((size_t)2 * FI * CH * 4);
  float* V     = (float*)alloc((size_t)2 * NT * 3 * FI * 16 * 4);
  unsigned short* Bpk = (unsigned short*)alloc((size_t)230400 * 2);
  unsigned short* Bxs = (unsigned short*)alloc((size_t)73728 * 2);
  unsigned short* Blin = (unsigned short*)alloc((size_t)15360 * 2);
  float* bc    = (float*)alloc(2 * 76 * 4);
  float* ampv  = (float*)alloc((size_t)NN * 4);
  float* attv  = (float*)alloc((size_t)NN * 4);
  float* invv  = (float*)alloc((size_t)NN * 4);
  float* avglog = (float*)alloc(256);
  float* bnsum = (float*)alloc(2 * FI * 4);
  float* pooled = (float*)alloc((size_t)NG * FI * 4);
  int* deg = (int*)alloc((size_t)NN * 4);
  int* off = (int*)alloc((size_t)(NN + 1) * 4);
  int* cur = (int*)alloc((size_t)NN * 4);
  int2* csr = (int2*)alloc((size_t)NE * 8);

  hipMemsetAsync(deg, 0, (size_t)NN * 4, stream);

  k_mega1<<<7562, 256, 0, stream>>>(x_idx, node_emb, x_a, dstp, deg,
                                    edge_emb, W_edge, b_edge, te,
                                    W_pre, WAs, W_post, V,
                                    b_post, W_lin, b_lin, bc);
  k_mega2<<<389, 1024, 0, stream>>>(deg, off, cur, avglog,
                                    te, W_pre, b_pre, tm_bf, W_post, V, Bpk,
                                    WAs, Bxs, W_lin, Blin);
  k_mega3<<<1329, 256, 0, stream>>>(srcp, dstp, eattr, cur, csr,
                                    deg, avglog, ampv, attv, invv);

  for (int l = 0; l < 2; ++l) {
    const float* xin = (l == 0) ? x_a : x_b;
    float* xout = (l == 0) ? x_b : x_a;
    k_gemm_xs<<<dim3(625, 2), 256, 0, stream>>>(xin, Bxs + (size_t)l * 36864,
                                                xs_bf, deg, xh, bnsum);
    k_aggpost<<<1250, 1024, 0, stream>>>(xs_bf, csr, off, invv,
                                         tm_bf + (size_t)l * 100 * 384, xh,
                                         Bpk + (size_t)l * 115200, ampv, attv,
                                         Blin + (size_t)l * 7680, bc + l * 76,
                                         z, bnsum);
    k_bnfinapply<<<1250, 256, 0, stream>>>(z, bnsum, gam + l * FI, bet + l * FI,
                                           xout, batch, pooled, (l == 1) ? 1 : 0);
  }

  k_head<<<NG, 64, 0, stream>>>(pooled, W1, b1, W2, b2, W3, b3, (float*)d_out);
}